// Round 8
// baseline (118.022 us; speedup 1.0000x reference)
//
#include <hip/hip_runtime.h>
#include <hip/hip_bf16.h>
#include <math.h>

#define DD 48
#define NN 512
#define TWO_D 96
#define ROWS 2048   // B*N = 4*512

typedef __attribute__((ext_vector_type(8))) short bf16x8;
typedef __attribute__((ext_vector_type(4))) float f32x4;

// Exact-erf GELU via degree-5 polynomial (ZERO transcendental ops).
// gelu(u) = u * (0.5 + uc*E(uc^2)), uc = clamp(u, +-3.5777).
// E = Newton interpolation of (Phi(u)-0.5)/u at v={0.2,1.5,4,7,10.2,12.8};
// verified |dE|<=3e-4 over the range -> |dh| <= ~6e-4 typical (below bf16 rounding).
// Tails: clamp gives h ~= u (u>3.58) / h ~= 0 (u<-3.58), err < 7e-4.
__device__ __forceinline__ float gelu_poly(float u) {
    const float uc = fminf(fmaxf(u, -3.5777f), 3.5777f);
    const float v = uc * uc;
    float E = fmaf(v, -1.04448e-6f, 4.61896e-5f);
    E = fmaf(v, E, -8.62284e-4f);
    E = fmaf(v, E, 9.22138e-3f);
    E = fmaf(v, E, -6.58353e-2f);
    E = fmaf(v, E, 3.98855e-1f);
    return u * fmaf(uc, E, 0.5f);
}

// Kernel 1: blocks 0..511: A[r][t] = x_r @ W1[:48,t] + b1[t]; Bb[r][t] = x_r @ W1[48:,t]
//           block 512:     W2T[f][k] = bf16(W2[k][f])
__global__ __launch_bounds__(256) void precompute_kernel(
        const float* __restrict__ x,
        const float* __restrict__ W1,
        const float* __restrict__ b1,
        const float* __restrict__ W2,
        float* __restrict__ Aout,
        float* __restrict__ Bout,
        __hip_bfloat16* __restrict__ W2T) {
    if (blockIdx.x == ROWS / 4) {
        for (int idx = threadIdx.x; idx < DD * TWO_D; idx += 256) {
            const int f = idx / TWO_D;
            const int k = idx - f * TWO_D;
            W2T[idx] = __float2bfloat16(W2[k * DD + f]);
        }
        return;
    }
    const int wave = threadIdx.x >> 6;
    const int lane = threadIdx.x & 63;
    const int row = blockIdx.x * 4 + wave;
    __shared__ float xs[4][DD];
    if (threadIdx.x < 4 * DD)
        xs[threadIdx.x / DD][threadIdx.x % DD] = x[blockIdx.x * 4 * DD + threadIdx.x];
    __syncthreads();
    for (int t = lane; t < TWO_D; t += 64) {
        float a0 = 0.f, a1 = 0.f;
#pragma unroll 8
        for (int k = 0; k < DD; ++k) {
            const float xv = xs[wave][k];
            a0 = fmaf(xv, W1[k * TWO_D + t], a0);
            a1 = fmaf(xv, W1[(DD + k) * TWO_D + t], a1);
        }
        Aout[row * TWO_D + t] = a0 + b1[t];
        Bout[row * TWO_D + t] = a1;
    }
}

// Kernel 2 (R5 skeleton + poly-gelu + operand-swapped MFMA):
// A-operand = W2T fragments, B-operand = H fragments (same lane data as before,
// only the intrinsic argument order changes). C/D: row = f_local = 4q+r,
// col = j_local = n  ->  ONE j per lane: epilogue is 2 shfl stages + 1 sqrt +
// 1 exp2 per chunk; o/l partials reduce over n once at kernel end.
__global__ __launch_bounds__(256, 4) void pair_softmax_kernel(
        const float* __restrict__ Arow,
        const float* __restrict__ Brow,
        const __hip_bfloat16* __restrict__ W2T,
        const float* __restrict__ b2,
        float* __restrict__ out) {
    // Epoch-balanced mapping (R5): every CU's 8 blocks have Sum(i) = const.
    const int e = blockIdx.x >> 8;          // 0..7
    const int p = blockIdx.x & 255;
    const int base = (e & 1) ? ((e >> 1) << 6) : (448 - ((e >> 1) << 6));
    const int off = (e & 1) ? (63 - (p >> 2)) : (p >> 2);
    const int i = base + off;
    const int row = (p & 3) * NN + i;

    const int tid = threadIdx.x;
    const int wave = tid >> 6;                 // 0..3
    const int lane = tid & 63;
    const int n = lane & 15;   // j-local (C/D col); also W2T A-frag row f-local
    const int q = lane >> 4;   // quad
    const int q8 = q * 8;

    const float* __restrict__ Bbase = Brow + (size_t)(row - i) * TWO_D;

    // W2T fragments (A-operand): lane holds W2T[f=t*16+n][ks*32+q8+0..7]
    bf16x8 bfrag[3][3];
#pragma unroll
    for (int t = 0; t < 3; ++t)
#pragma unroll
        for (int ks = 0; ks < 3; ++ks)
            bfrag[t][ks] = *(const bf16x8*)&W2T[(t * 16 + n) * TWO_D + ks * 32 + q8];
    // b2 for this lane's C/D rows: f = t*16 + 4q + r
    float b2v[3][4];
#pragma unroll
    for (int t = 0; t < 3; ++t)
#pragma unroll
        for (int r = 0; r < 4; ++r) b2v[t][r] = b2[t * 16 + 4 * q + r];

    // A_i values this lane needs: k = ks*32 + q8 + 0..7
    float av[3][8];
#pragma unroll
    for (int ks = 0; ks < 3; ++ks) {
        const float4 a0 = *(const float4*)&Arow[(size_t)row * TWO_D + ks * 32 + q8];
        const float4 a1 = *(const float4*)&Arow[(size_t)row * TWO_D + ks * 32 + q8 + 4];
        av[ks][0] = a0.x; av[ks][1] = a0.y; av[ks][2] = a0.z; av[ks][3] = a0.w;
        av[ks][4] = a1.x; av[ks][5] = a1.y; av[ks][6] = a1.z; av[ks][7] = a1.w;
    }

    float l_run = 0.f;
    float o_run[3][4] = {{0.f,0.f,0.f,0.f},{0.f,0.f,0.f,0.f},{0.f,0.f,0.f,0.f}};

    const int nchunks = (i + 16) >> 4;   // ceil((i+1)/16)
    const ptrdiff_t cstep = 64 * TWO_D;  // 4 chunks ahead

    // Rolling register prefetch (constant-indexed -> stays in VGPRs; R5-proven)
    const float* __restrict__ Bj = Bbase + (size_t)(wave * 16 + n) * TWO_D;
    float4 pb[6];
    if (wave < nchunks) {
#pragma unroll
        for (int ks = 0; ks < 3; ++ks) {
            pb[2 * ks]     = *(const float4*)&Bj[ks * 32 + q8];
            pb[2 * ks + 1] = *(const float4*)&Bj[ks * 32 + q8 + 4];
        }
    }

    for (int c = wave; c < nchunks; c += 4) {
        const int j0 = c << 4;
        const bool hn = (c + 4) < nchunks;     // wave-uniform
        const float* __restrict__ Bjn = Bj + cstep;

        f32x4 acc[3] = {{0.f,0.f,0.f,0.f},{0.f,0.f,0.f,0.f},{0.f,0.f,0.f,0.f}};
#pragma unroll
        for (int ks = 0; ks < 3; ++ks) {
            const float4 bv0 = pb[2 * ks];
            const float4 bv1 = pb[2 * ks + 1];
            if (hn) {   // next chunk's loads in flight during compute
                pb[2 * ks]     = *(const float4*)&Bjn[ks * 32 + q8];
                pb[2 * ks + 1] = *(const float4*)&Bjn[ks * 32 + q8 + 4];
            }
            float h[8];
            h[0] = gelu_poly(av[ks][0] + bv0.x);
            h[1] = gelu_poly(av[ks][1] + bv0.y);
            h[2] = gelu_poly(av[ks][2] + bv0.z);
            h[3] = gelu_poly(av[ks][3] + bv0.w);
            h[4] = gelu_poly(av[ks][4] + bv1.x);
            h[5] = gelu_poly(av[ks][5] + bv1.y);
            h[6] = gelu_poly(av[ks][6] + bv1.z);
            h[7] = gelu_poly(av[ks][7] + bv1.w);
            union { bf16x8 v; __hip_bfloat162 h2[4]; } hf;
#pragma unroll
            for (int pp = 0; pp < 4; ++pp)
                hf.h2[pp] = __float22bfloat162_rn(make_float2(h[2 * pp], h[2 * pp + 1]));
            // D[f][j] += W2T-tile (A) x H^T (B): lane data unchanged, args swapped
            acc[0] = __builtin_amdgcn_mfma_f32_16x16x32_bf16(bfrag[0][ks], hf.v, acc[0], 0, 0, 0);
            acc[1] = __builtin_amdgcn_mfma_f32_16x16x32_bf16(bfrag[1][ks], hf.v, acc[1], 0, 0, 0);
            acc[2] = __builtin_amdgcn_mfma_f32_16x16x32_bf16(bfrag[2][ks], hf.v, acc[2], 0, 0, 0);
        }
        Bj = Bjn;

        // ---- Epilogue: lane holds P[f=t*16+4q+r][j=j0+n]
        float pv[3][4];
        float ss = 0.f;
#pragma unroll
        for (int t = 0; t < 3; ++t)
#pragma unroll
            for (int r = 0; r < 4; ++r) {
                const float pz = acc[t][r] + b2v[t][r];
                pv[t][r] = pz;
                ss = fmaf(pz, pz, ss);
            }
        // full ||p_j||^2: reduce the 4 q-partials (2 stages)
        ss += __shfl_xor(ss, 16);
        ss += __shfl_xor(ss, 32);
        const int j = j0 + n;
        const float ew = (j <= i)
            ? __builtin_amdgcn_exp2f(sqrtf(ss) * 1.44269504f) : 0.f;
        l_run += ew;      // same value in all 4 q-copies; n-reduce at end dedups
#pragma unroll
        for (int t = 0; t < 3; ++t)
#pragma unroll
            for (int r = 0; r < 4; ++r)
                o_run[t][r] = fmaf(ew, pv[t][r], o_run[t][r]);
    }

    // ---- Final reduce over n (16 lanes; q bits untouched -> l not quadrupled)
#pragma unroll
    for (int d = 1; d <= 8; d <<= 1) {
        l_run += __shfl_xor(l_run, d);
#pragma unroll
        for (int t = 0; t < 3; ++t)
#pragma unroll
            for (int r = 0; r < 4; ++r)
                o_run[t][r] += __shfl_xor(o_run[t][r], d);
    }
    __shared__ float lred[4];
    __shared__ float ored[4][DD];
    if (n == 0) {
#pragma unroll
        for (int t = 0; t < 3; ++t)
#pragma unroll
            for (int r = 0; r < 4; ++r)
                ored[wave][t * 16 + 4 * q + r] = o_run[t][r];
    }
    if (lane == 0) lred[wave] = l_run;
    __syncthreads();
    if (tid < DD) {
        float L = 0.f, O = 0.f;
#pragma unroll
        for (int wv = 0; wv < 4; ++wv) {
            L += lred[wv];
            O += ored[wv][tid];
        }
        out[row * DD + tid] = O / L;
    }
}

extern "C" void kernel_launch(void* const* d_in, const int* in_sizes, int n_in,
                              void* d_out, int out_size, void* d_ws, size_t ws_size,
                              hipStream_t stream) {
    const float* x  = (const float*)d_in[0];
    const float* W1 = (const float*)d_in[1];
    const float* b1 = (const float*)d_in[2];
    const float* W2 = (const float*)d_in[3];
    const float* b2 = (const float*)d_in[4];
    float* outp = (float*)d_out;

    float* A  = (float*)d_ws;                           // 2048*96 fp32
    float* Bb = A + ROWS * TWO_D;                       // 2048*96 fp32
    __hip_bfloat16* W2T = (__hip_bfloat16*)(Bb + ROWS * TWO_D);  // 48*96 bf16

    precompute_kernel<<<ROWS / 4 + 1, 256, 0, stream>>>(x, W1, b1, W2, A, Bb, W2T);
    pair_softmax_kernel<<<ROWS, 256, 0, stream>>>(A, Bb, W2T, b2, outp);
}

// Round 9
// 101.619 us; speedup vs baseline: 1.1614x; 1.1614x over previous
//
#include <hip/hip_runtime.h>
#include <hip/hip_bf16.h>
#include <math.h>

#define DD 48
#define NN 512
#define TWO_D 96
#define ROWS 2048   // B*N = 4*512

typedef __attribute__((ext_vector_type(8))) short bf16x8;
typedef __attribute__((ext_vector_type(4))) float f32x4;

// Exact-erf GELU via degree-5 polynomial (ZERO transcendental ops).
// gelu(u) = u * (0.5 + uc*E(uc^2)), uc = clamp(u, +-3.5777).
// Verified in R8 (passed, absmax 0.0039).
__device__ __forceinline__ float gelu_poly(float u) {
    const float uc = fminf(fmaxf(u, -3.5777f), 3.5777f);
    const float v = uc * uc;
    float E = fmaf(v, -1.04448e-6f, 4.61896e-5f);
    E = fmaf(v, E, -8.62284e-4f);
    E = fmaf(v, E, 9.22138e-3f);
    E = fmaf(v, E, -6.58353e-2f);
    E = fmaf(v, E, 3.98855e-1f);
    return u * fmaf(uc, E, 0.5f);
}

// Kernel 1: blocks 0..511: A[r][t] = x_r @ W1[:48,t] + b1[t]; Bb[r][t] = x_r @ W1[48:,t]
//           block 512:     W2T[f][k] = bf16(W2[k][f])
__global__ __launch_bounds__(256) void precompute_kernel(
        const float* __restrict__ x,
        const float* __restrict__ W1,
        const float* __restrict__ b1,
        const float* __restrict__ W2,
        float* __restrict__ Aout,
        float* __restrict__ Bout,
        __hip_bfloat16* __restrict__ W2T) {
    if (blockIdx.x == ROWS / 4) {
        for (int idx = threadIdx.x; idx < DD * TWO_D; idx += 256) {
            const int f = idx / TWO_D;
            const int k = idx - f * TWO_D;
            W2T[idx] = __float2bfloat16(W2[k * DD + f]);
        }
        return;
    }
    const int wave = threadIdx.x >> 6;
    const int lane = threadIdx.x & 63;
    const int row = blockIdx.x * 4 + wave;
    __shared__ float xs[4][DD];
    if (threadIdx.x < 4 * DD)
        xs[threadIdx.x / DD][threadIdx.x % DD] = x[blockIdx.x * 4 * DD + threadIdx.x];
    __syncthreads();
    for (int t = lane; t < TWO_D; t += 64) {
        float a0 = 0.f, a1 = 0.f;
#pragma unroll 8
        for (int k = 0; k < DD; ++k) {
            const float xv = xs[wave][k];
            a0 = fmaf(xv, W1[k * TWO_D + t], a0);
            a1 = fmaf(xv, W1[(DD + k) * TWO_D + t], a1);
        }
        Aout[row * TWO_D + t] = a0 + b1[t];
        Bout[row * TWO_D + t] = a1;
    }
}

// Kernel 2: R8 algorithm (poly-gelu + operand-swapped MFMA epilogue) with the
// register cap REMOVED — no __launch_bounds__ min-waves arg, so no scratch spills.
// C/D layout: row = f_local = 4q+r, col = j_local = n -> one j per lane:
// per-chunk epilogue = 2 shfl + 1 sqrt + 1 exp2; o/l n-reduce deferred to end.
__global__ __launch_bounds__(256) void pair_softmax_kernel(
        const float* __restrict__ Arow,
        const float* __restrict__ Brow,
        const __hip_bfloat16* __restrict__ W2T,
        const float* __restrict__ b2,
        float* __restrict__ out) {
    // Epoch-balanced mapping (R5): every CU's 8 blocks have Sum(i) = const.
    const int e = blockIdx.x >> 8;          // 0..7
    const int p = blockIdx.x & 255;
    const int base = (e & 1) ? ((e >> 1) << 6) : (448 - ((e >> 1) << 6));
    const int off = (e & 1) ? (63 - (p >> 2)) : (p >> 2);
    const int i = base + off;
    const int row = (p & 3) * NN + i;

    const int tid = threadIdx.x;
    const int wave = tid >> 6;                 // 0..3
    const int lane = tid & 63;
    const int n = lane & 15;   // j-local (C/D col); also W2T A-frag row f-local
    const int q = lane >> 4;   // quad
    const int q8 = q * 8;

    const float* __restrict__ Bbase = Brow + (size_t)(row - i) * TWO_D;

    // W2T fragments (A-operand): lane holds W2T[f=t*16+n][ks*32+q8+0..7]
    bf16x8 bfrag[3][3];
#pragma unroll
    for (int t = 0; t < 3; ++t)
#pragma unroll
        for (int ks = 0; ks < 3; ++ks)
            bfrag[t][ks] = *(const bf16x8*)&W2T[(t * 16 + n) * TWO_D + ks * 32 + q8];
    // b2 for this lane's C/D rows: f = t*16 + 4q + r
    float b2v[3][4];
#pragma unroll
    for (int t = 0; t < 3; ++t)
#pragma unroll
        for (int r = 0; r < 4; ++r) b2v[t][r] = b2[t * 16 + 4 * q + r];

    // A_i values this lane needs: k = ks*32 + q8 + 0..7
    float av[3][8];
#pragma unroll
    for (int ks = 0; ks < 3; ++ks) {
        const float4 a0 = *(const float4*)&Arow[(size_t)row * TWO_D + ks * 32 + q8];
        const float4 a1 = *(const float4*)&Arow[(size_t)row * TWO_D + ks * 32 + q8 + 4];
        av[ks][0] = a0.x; av[ks][1] = a0.y; av[ks][2] = a0.z; av[ks][3] = a0.w;
        av[ks][4] = a1.x; av[ks][5] = a1.y; av[ks][6] = a1.z; av[ks][7] = a1.w;
    }

    float l_run = 0.f;
    float o_run[3][4] = {{0.f,0.f,0.f,0.f},{0.f,0.f,0.f,0.f},{0.f,0.f,0.f,0.f}};

    const int nchunks = (i + 16) >> 4;   // ceil((i+1)/16)
    const ptrdiff_t cstep = 64 * TWO_D;  // 4 chunks ahead

    // Rolling register prefetch (constant-indexed -> stays in VGPRs)
    const float* __restrict__ Bj = Bbase + (size_t)(wave * 16 + n) * TWO_D;
    float4 pb[6];
    if (wave < nchunks) {
#pragma unroll
        for (int ks = 0; ks < 3; ++ks) {
            pb[2 * ks]     = *(const float4*)&Bj[ks * 32 + q8];
            pb[2 * ks + 1] = *(const float4*)&Bj[ks * 32 + q8 + 4];
        }
    }

    for (int c = wave; c < nchunks; c += 4) {
        const int j0 = c << 4;
        const bool hn = (c + 4) < nchunks;     // wave-uniform
        const float* __restrict__ Bjn = Bj + cstep;

        f32x4 acc[3] = {{0.f,0.f,0.f,0.f},{0.f,0.f,0.f,0.f},{0.f,0.f,0.f,0.f}};
#pragma unroll
        for (int ks = 0; ks < 3; ++ks) {
            const float4 bv0 = pb[2 * ks];
            const float4 bv1 = pb[2 * ks + 1];
            if (hn) {   // next chunk's loads in flight during compute
                pb[2 * ks]     = *(const float4*)&Bjn[ks * 32 + q8];
                pb[2 * ks + 1] = *(const float4*)&Bjn[ks * 32 + q8 + 4];
            }
            float h[8];
            h[0] = gelu_poly(av[ks][0] + bv0.x);
            h[1] = gelu_poly(av[ks][1] + bv0.y);
            h[2] = gelu_poly(av[ks][2] + bv0.z);
            h[3] = gelu_poly(av[ks][3] + bv0.w);
            h[4] = gelu_poly(av[ks][4] + bv1.x);
            h[5] = gelu_poly(av[ks][5] + bv1.y);
            h[6] = gelu_poly(av[ks][6] + bv1.z);
            h[7] = gelu_poly(av[ks][7] + bv1.w);
            union { bf16x8 v; __hip_bfloat162 h2[4]; } hf;
#pragma unroll
            for (int pp = 0; pp < 4; ++pp)
                hf.h2[pp] = __float22bfloat162_rn(make_float2(h[2 * pp], h[2 * pp + 1]));
            // D[f][j] += W2T-tile (A) x H^T (B)
            acc[0] = __builtin_amdgcn_mfma_f32_16x16x32_bf16(bfrag[0][ks], hf.v, acc[0], 0, 0, 0);
            acc[1] = __builtin_amdgcn_mfma_f32_16x16x32_bf16(bfrag[1][ks], hf.v, acc[1], 0, 0, 0);
            acc[2] = __builtin_amdgcn_mfma_f32_16x16x32_bf16(bfrag[2][ks], hf.v, acc[2], 0, 0, 0);
        }
        Bj = Bjn;

        // ---- Epilogue: lane holds P[f=t*16+4q+r][j=j0+n]
        float pv[3][4];
        float ss = 0.f;
#pragma unroll
        for (int t = 0; t < 3; ++t)
#pragma unroll
            for (int r = 0; r < 4; ++r) {
                const float pz = acc[t][r] + b2v[t][r];
                pv[t][r] = pz;
                ss = fmaf(pz, pz, ss);
            }
        // full ||p_j||^2: reduce the 4 q-partials (2 stages)
        ss += __shfl_xor(ss, 16);
        ss += __shfl_xor(ss, 32);
        const int j = j0 + n;
        const float ew = (j <= i)
            ? __builtin_amdgcn_exp2f(sqrtf(ss) * 1.44269504f) : 0.f;
        l_run += ew;      // same value in all 4 q-copies; n-reduce at end dedups
#pragma unroll
        for (int t = 0; t < 3; ++t)
#pragma unroll
            for (int r = 0; r < 4; ++r)
                o_run[t][r] = fmaf(ew, pv[t][r], o_run[t][r]);
    }

    // ---- Final reduce over n (16 lanes; q bits untouched -> l not quadrupled)
#pragma unroll
    for (int d = 1; d <= 8; d <<= 1) {
        l_run += __shfl_xor(l_run, d);
#pragma unroll
        for (int t = 0; t < 3; ++t)
#pragma unroll
            for (int r = 0; r < 4; ++r)
                o_run[t][r] += __shfl_xor(o_run[t][r], d);
    }
    __shared__ float lred[4];
    __shared__ float ored[4][DD];
    if (n == 0) {
#pragma unroll
        for (int t = 0; t < 3; ++t)
#pragma unroll
            for (int r = 0; r < 4; ++r)
                ored[wave][t * 16 + 4 * q + r] = o_run[t][r];
    }
    if (lane == 0) lred[wave] = l_run;
    __syncthreads();
    if (tid < DD) {
        float L = 0.f, O = 0.f;
#pragma unroll
        for (int wv = 0; wv < 4; ++wv) {
            L += lred[wv];
            O += ored[wv][tid];
        }
        out[row * DD + tid] = O / L;
    }
}

extern "C" void kernel_launch(void* const* d_in, const int* in_sizes, int n_in,
                              void* d_out, int out_size, void* d_ws, size_t ws_size,
                              hipStream_t stream) {
    const float* x  = (const float*)d_in[0];
    const float* W1 = (const float*)d_in[1];
    const float* b1 = (const float*)d_in[2];
    const float* W2 = (const float*)d_in[3];
    const float* b2 = (const float*)d_in[4];
    float* outp = (float*)d_out;

    float* A  = (float*)d_ws;                           // 2048*96 fp32
    float* Bb = A + ROWS * TWO_D;                       // 2048*96 fp32
    __hip_bfloat16* W2T = (__hip_bfloat16*)(Bb + ROWS * TWO_D);  // 48*96 bf16

    precompute_kernel<<<ROWS / 4 + 1, 256, 0, stream>>>(x, W1, b1, W2, A, Bb, W2T);
    pair_softmax_kernel<<<ROWS, 256, 0, stream>>>(A, Bb, W2T, b2, outp);
}

// Round 10
// 97.697 us; speedup vs baseline: 1.2080x; 1.0401x over previous
//
#include <hip/hip_runtime.h>
#include <hip/hip_bf16.h>
#include <math.h>

#define DD 48
#define NN 512
#define TWO_D 96
#define ROWS 2048   // B*N = 4*512

typedef __attribute__((ext_vector_type(8))) short bf16x8;
typedef __attribute__((ext_vector_type(4))) float f32x4;

// Exact-erf GELU via degree-5 polynomial (ZERO transcendental ops).
// gelu(u) = u * (0.5 + uc*E(uc^2)), uc = clamp(u, +-3.5777). R8/R9-verified.
__device__ __forceinline__ float gelu_poly(float u) {
    const float uc = fminf(fmaxf(u, -3.5777f), 3.5777f);
    const float v = uc * uc;
    float E = fmaf(v, -1.04448e-6f, 4.61896e-5f);
    E = fmaf(v, E, -8.62284e-4f);
    E = fmaf(v, E, 9.22138e-3f);
    E = fmaf(v, E, -6.58353e-2f);
    E = fmaf(v, E, 3.98855e-1f);
    return u * fmaf(uc, E, 0.5f);
}

// Kernel 1: blocks 0..511: A[r][t] = x_r @ W1[:48,t] + b1[t]; Bb[r][t] = x_r @ W1[48:,t]
//           block 512:     W2T[f][k] = bf16(W2[k][f])
__global__ __launch_bounds__(256) void precompute_kernel(
        const float* __restrict__ x,
        const float* __restrict__ W1,
        const float* __restrict__ b1,
        const float* __restrict__ W2,
        float* __restrict__ Aout,
        float* __restrict__ Bout,
        __hip_bfloat16* __restrict__ W2T) {
    if (blockIdx.x == ROWS / 4) {
        for (int idx = threadIdx.x; idx < DD * TWO_D; idx += 256) {
            const int f = idx / TWO_D;
            const int k = idx - f * TWO_D;
            W2T[idx] = __float2bfloat16(W2[k * DD + f]);
        }
        return;
    }
    const int wave = threadIdx.x >> 6;
    const int lane = threadIdx.x & 63;
    const int row = blockIdx.x * 4 + wave;
    __shared__ float xs[4][DD];
    if (threadIdx.x < 4 * DD)
        xs[threadIdx.x / DD][threadIdx.x % DD] = x[blockIdx.x * 4 * DD + threadIdx.x];
    __syncthreads();
    for (int t = lane; t < TWO_D; t += 64) {
        float a0 = 0.f, a1 = 0.f;
#pragma unroll 8
        for (int k = 0; k < DD; ++k) {
            const float xv = xs[wave][k];
            a0 = fmaf(xv, W1[k * TWO_D + t], a0);
            a1 = fmaf(xv, W1[(DD + k) * TWO_D + t], a1);
        }
        Aout[row * TWO_D + t] = a0 + b1[t];
        Bout[row * TWO_D + t] = a1;
    }
}

// Per-row processing loop: R9's proven engine (rolling constant-indexed pb[6]
// prefetch, poly-gelu, operand-swapped MFMA: C/D row=f_local=4q+r, col=j=n).
// Textual macro (NOT a lambda/function) so register allocation matches R9.
#define PROCESS_ROW(I_, ROW_, CSTART_, lacc_, oacc_)                              \
  {                                                                               \
    float av[3][8];                                                               \
    _Pragma("unroll")                                                             \
    for (int ks = 0; ks < 3; ++ks) {                                              \
      const float4 a0 = *(const float4*)&Arow[(size_t)(ROW_)*TWO_D + ks*32 + q8]; \
      const float4 a1 = *(const float4*)&Arow[(size_t)(ROW_)*TWO_D + ks*32 + q8 + 4]; \
      av[ks][0]=a0.x; av[ks][1]=a0.y; av[ks][2]=a0.z; av[ks][3]=a0.w;             \
      av[ks][4]=a1.x; av[ks][5]=a1.y; av[ks][6]=a1.z; av[ks][7]=a1.w;             \
    }                                                                             \
    const int nch = ((I_) + 16) >> 4;                                             \
    const float* __restrict__ Bj = Bbase + (size_t)(((CSTART_) << 4) + n) * TWO_D;\
    float4 pb[6];                                                                 \
    if ((CSTART_) < nch) {                                                        \
      _Pragma("unroll")                                                           \
      for (int ks = 0; ks < 3; ++ks) {                                            \
        pb[2*ks]   = *(const float4*)&Bj[ks*32 + q8];                             \
        pb[2*ks+1] = *(const float4*)&Bj[ks*32 + q8 + 4];                         \
      }                                                                           \
    }                                                                             \
    for (int c = (CSTART_); c < nch; c += 4) {                                    \
      const int j0 = c << 4;                                                      \
      const bool hn = (c + 4) < nch;                                              \
      const float* __restrict__ Bjn = Bj + (ptrdiff_t)(64 * TWO_D);               \
      f32x4 acc[3] = {{0.f,0.f,0.f,0.f},{0.f,0.f,0.f,0.f},{0.f,0.f,0.f,0.f}};     \
      _Pragma("unroll")                                                           \
      for (int ks = 0; ks < 3; ++ks) {                                            \
        const float4 bv0 = pb[2*ks];                                              \
        const float4 bv1 = pb[2*ks+1];                                            \
        if (hn) {                                                                 \
          pb[2*ks]   = *(const float4*)&Bjn[ks*32 + q8];                          \
          pb[2*ks+1] = *(const float4*)&Bjn[ks*32 + q8 + 4];                      \
        }                                                                         \
        float h[8];                                                               \
        h[0] = gelu_poly(av[ks][0] + bv0.x);                                      \
        h[1] = gelu_poly(av[ks][1] + bv0.y);                                      \
        h[2] = gelu_poly(av[ks][2] + bv0.z);                                      \
        h[3] = gelu_poly(av[ks][3] + bv0.w);                                      \
        h[4] = gelu_poly(av[ks][4] + bv1.x);                                      \
        h[5] = gelu_poly(av[ks][5] + bv1.y);                                      \
        h[6] = gelu_poly(av[ks][6] + bv1.z);                                      \
        h[7] = gelu_poly(av[ks][7] + bv1.w);                                      \
        union { bf16x8 v; __hip_bfloat162 h2[4]; } hf;                            \
        _Pragma("unroll")                                                         \
        for (int pp = 0; pp < 4; ++pp)                                            \
          hf.h2[pp] = __float22bfloat162_rn(make_float2(h[2*pp], h[2*pp+1]));     \
        acc[0] = __builtin_amdgcn_mfma_f32_16x16x32_bf16(bfrag[0][ks], hf.v, acc[0], 0, 0, 0); \
        acc[1] = __builtin_amdgcn_mfma_f32_16x16x32_bf16(bfrag[1][ks], hf.v, acc[1], 0, 0, 0); \
        acc[2] = __builtin_amdgcn_mfma_f32_16x16x32_bf16(bfrag[2][ks], hf.v, acc[2], 0, 0, 0); \
      }                                                                           \
      Bj = Bjn;                                                                   \
      float pv[3][4];                                                             \
      float ss = 0.f;                                                             \
      _Pragma("unroll")                                                           \
      for (int t = 0; t < 3; ++t)                                                 \
        _Pragma("unroll")                                                         \
        for (int r = 0; r < 4; ++r) {                                             \
          const float pz = acc[t][r] + b2v[t][r];                                 \
          pv[t][r] = pz;                                                          \
          ss = fmaf(pz, pz, ss);                                                  \
        }                                                                         \
      ss += __shfl_xor(ss, 16);                                                   \
      ss += __shfl_xor(ss, 32);                                                   \
      const int j = j0 + n;                                                       \
      const float ew = (j <= (I_))                                                \
          ? __builtin_amdgcn_exp2f(sqrtf(ss) * 1.44269504f) : 0.f;                \
      lacc_ += ew;                                                                \
      _Pragma("unroll")                                                           \
      for (int t = 0; t < 3; ++t)                                                 \
        _Pragma("unroll")                                                         \
        for (int r = 0; r < 4; ++r)                                               \
          oacc_[t][r] = fmaf(ew, pv[t][r], oacc_[t][r]);                          \
    }                                                                             \
  }

// Kernel 2: one block per (batch, row-PAIR (p, 511-p)); cH+cL = 33 chunks for
// EVERY block -> 1024 identical blocks = exactly 4 blocks/CU, all co-resident,
// simultaneous finish (no drain tail). Each wave: heavy-row chunks c=w,w+4,..,
// then light-row chunks continuing the mod-4 sequence (8-9 chunks/wave total).
__global__ __launch_bounds__(256) void pair_softmax_kernel(
        const float* __restrict__ Arow,
        const float* __restrict__ Brow,
        const __hip_bfloat16* __restrict__ W2T,
        const float* __restrict__ b2,
        float* __restrict__ out) {
    const int batch = blockIdx.x >> 8;        // 0..3
    const int pr = blockIdx.x & 255;          // 0..255
    const int iH = (NN - 1) - pr;             // 256..511
    const int iL = pr;                        // 0..255
    const int cH = (iH >> 4) + 1;             // 17..32; cH + cL = 33
    const int rowH = batch * NN + iH;
    const int rowL = batch * NN + iL;
    const float* __restrict__ Bbase = Brow + (size_t)batch * NN * TWO_D;

    const int tid = threadIdx.x;
    const int wave = tid >> 6;                // 0..3
    const int lane = tid & 63;
    const int n = lane & 15;   // j-local (C/D col); also W2T A-frag row f-local
    const int q = lane >> 4;   // quad
    const int q8 = q * 8;

    // W2T fragments (A-operand): lane holds W2T[f=t*16+n][ks*32+q8+0..7]
    bf16x8 bfrag[3][3];
#pragma unroll
    for (int t = 0; t < 3; ++t)
#pragma unroll
        for (int ks = 0; ks < 3; ++ks)
            bfrag[t][ks] = *(const bf16x8*)&W2T[(t * 16 + n) * TWO_D + ks * 32 + q8];
    // b2 for this lane's C/D rows: f = t*16 + 4q + r (shared by both rows)
    float b2v[3][4];
#pragma unroll
    for (int t = 0; t < 3; ++t)
#pragma unroll
        for (int r = 0; r < 4; ++r) b2v[t][r] = b2[t * 16 + 4 * q + r];

    float lH = 0.f, lL = 0.f;
    float oH[3][4] = {{0.f,0.f,0.f,0.f},{0.f,0.f,0.f,0.f},{0.f,0.f,0.f,0.f}};
    float oL[3][4] = {{0.f,0.f,0.f,0.f},{0.f,0.f,0.f,0.f},{0.f,0.f,0.f,0.f}};

    // Heavy row: chunks c ≡ wave (mod 4), c < cH
    PROCESS_ROW(iH, rowH, wave, lH, oH);
    // Light row: global chunk index idx = cH + c ≡ wave (mod 4)
    const int cstartL = (wave + 128 - cH) & 3;
    PROCESS_ROW(iL, rowL, cstartL, lL, oL);

    // ---- Final reduce over n (16 lanes; q bits untouched)
#pragma unroll
    for (int d = 1; d <= 8; d <<= 1) {
        lH += __shfl_xor(lH, d);
        lL += __shfl_xor(lL, d);
#pragma unroll
        for (int t = 0; t < 3; ++t)
#pragma unroll
            for (int r = 0; r < 4; ++r) {
                oH[t][r] += __shfl_xor(oH[t][r], d);
                oL[t][r] += __shfl_xor(oL[t][r], d);
            }
    }
    __shared__ float lred[4][2];
    __shared__ float ored[4][2][DD];
    if (n == 0) {
#pragma unroll
        for (int t = 0; t < 3; ++t)
#pragma unroll
            for (int r = 0; r < 4; ++r) {
                ored[wave][0][t * 16 + 4 * q + r] = oH[t][r];
                ored[wave][1][t * 16 + 4 * q + r] = oL[t][r];
            }
    }
    if (lane == 0) { lred[wave][0] = lH; lred[wave][1] = lL; }
    __syncthreads();
    if (tid < 2 * DD) {
        const int sel = tid / DD;
        const int f = tid - sel * DD;
        float L = 0.f, O = 0.f;
#pragma unroll
        for (int wv = 0; wv < 4; ++wv) {
            L += lred[wv][sel];
            O += ored[wv][sel][f];
        }
        const int row = sel ? rowL : rowH;
        out[row * DD + f] = O / L;
    }
}

extern "C" void kernel_launch(void* const* d_in, const int* in_sizes, int n_in,
                              void* d_out, int out_size, void* d_ws, size_t ws_size,
                              hipStream_t stream) {
    const float* x  = (const float*)d_in[0];
    const float* W1 = (const float*)d_in[1];
    const float* b1 = (const float*)d_in[2];
    const float* W2 = (const float*)d_in[3];
    const float* b2 = (const float*)d_in[4];
    float* outp = (float*)d_out;

    float* A  = (float*)d_ws;                           // 2048*96 fp32
    float* Bb = A + ROWS * TWO_D;                       // 2048*96 fp32
    __hip_bfloat16* W2T = (__hip_bfloat16*)(Bb + ROWS * TWO_D);  // 48*96 bf16

    precompute_kernel<<<ROWS / 4 + 1, 256, 0, stream>>>(x, W1, b1, W2, A, Bb, W2T);
    pair_softmax_kernel<<<1024, 256, 0, stream>>>(A, Bb, W2T, b2, outp);
}

// Round 11
// 92.072 us; speedup vs baseline: 1.2818x; 1.0611x over previous
//
#include <hip/hip_runtime.h>
#include <hip/hip_bf16.h>
#include <math.h>

#define DD 48
#define NN 512
#define TWO_D 96
#define ROWS 2048   // B*N = 4*512

typedef __attribute__((ext_vector_type(8))) short bf16x8;
typedef __attribute__((ext_vector_type(4))) float f32x4;
typedef __attribute__((ext_vector_type(4))) unsigned int u32x4;

// Exact-erf GELU via degree-5 polynomial (ZERO transcendental ops). R8/R9-verified.
__device__ __forceinline__ float gelu_poly(float u) {
    const float uc = fminf(fmaxf(u, -3.5777f), 3.5777f);
    const float v = uc * uc;
    float E = fmaf(v, -1.04448e-6f, 4.61896e-5f);
    E = fmaf(v, E, -8.62284e-4f);
    E = fmaf(v, E, 9.22138e-3f);
    E = fmaf(v, E, -6.58353e-2f);
    E = fmaf(v, E, 3.98855e-1f);
    return u * fmaf(uc, E, 0.5f);
}

// bf16 pair unpack (1 VALU op each)
__device__ __forceinline__ float bflo(unsigned int u) { return __uint_as_float(u << 16); }
__device__ __forceinline__ float bfhi(unsigned int u) { return __uint_as_float(u & 0xffff0000u); }

// Kernel 1: blocks 0..511: A[r][t] = x_r @ W1[:48,t] + b1[t] (fp32);
//           Bb[r][t] = bf16(x_r @ W1[48:,t]); block 512: W2T[f][k] = bf16(W2[k][f])
__global__ __launch_bounds__(256) void precompute_kernel(
        const float* __restrict__ x,
        const float* __restrict__ W1,
        const float* __restrict__ b1,
        const float* __restrict__ W2,
        float* __restrict__ Aout,
        __hip_bfloat16* __restrict__ Bout,
        __hip_bfloat16* __restrict__ W2T) {
    if (blockIdx.x == ROWS / 4) {
        for (int idx = threadIdx.x; idx < DD * TWO_D; idx += 256) {
            const int f = idx / TWO_D;
            const int k = idx - f * TWO_D;
            W2T[idx] = __float2bfloat16(W2[k * DD + f]);
        }
        return;
    }
    const int wave = threadIdx.x >> 6;
    const int lane = threadIdx.x & 63;
    const int row = blockIdx.x * 4 + wave;
    __shared__ float xs[4][DD];
    if (threadIdx.x < 4 * DD)
        xs[threadIdx.x / DD][threadIdx.x % DD] = x[blockIdx.x * 4 * DD + threadIdx.x];
    __syncthreads();
    for (int t = lane; t < TWO_D; t += 64) {
        float a0 = 0.f, a1 = 0.f;
#pragma unroll 8
        for (int k = 0; k < DD; ++k) {
            const float xv = xs[wave][k];
            a0 = fmaf(xv, W1[k * TWO_D + t], a0);
            a1 = fmaf(xv, W1[(DD + k) * TWO_D + t], a1);
        }
        Aout[row * TWO_D + t] = a0 + b1[t];
        Bout[row * TWO_D + t] = __float2bfloat16(a1);
    }
}

// ---- building-block macros (textual, constant-indexed => registers, no spills)

#define LOAD_PB(PB_, PTR_)                                                      \
  { _Pragma("unroll")                                                           \
    for (int ks = 0; ks < 3; ++ks)                                              \
      PB_[ks] = *(const u32x4*)&(PTR_)[ks * 32 + q8]; }

// gelu+pack+3 MFMA for one chunk; optionally prefetch the stream's next chunk
#define CHUNK_MFMA(PB_, ACC_, PF_, NPTR_)                                       \
  { _Pragma("unroll")                                                           \
    for (int ks = 0; ks < 3; ++ks) {                                            \
      const unsigned int w0 = PB_[ks].x, w1 = PB_[ks].y,                        \
                         w2 = PB_[ks].z, w3 = PB_[ks].w;                        \
      if (PF_) PB_[ks] = *(const u32x4*)&(NPTR_)[ks * 32 + q8];                 \
      float h[8];                                                               \
      h[0] = gelu_poly(av[ks][0] + bflo(w0));                                   \
      h[1] = gelu_poly(av[ks][1] + bfhi(w0));                                   \
      h[2] = gelu_poly(av[ks][2] + bflo(w1));                                   \
      h[3] = gelu_poly(av[ks][3] + bfhi(w1));                                   \
      h[4] = gelu_poly(av[ks][4] + bflo(w2));                                   \
      h[5] = gelu_poly(av[ks][5] + bfhi(w2));                                   \
      h[6] = gelu_poly(av[ks][6] + bflo(w3));                                   \
      h[7] = gelu_poly(av[ks][7] + bfhi(w3));                                   \
      union { bf16x8 v; __hip_bfloat162 h2[4]; } hf;                            \
      _Pragma("unroll")                                                         \
      for (int pp = 0; pp < 4; ++pp)                                            \
        hf.h2[pp] = __float22bfloat162_rn(make_float2(h[2*pp], h[2*pp+1]));     \
      ACC_[0] = __builtin_amdgcn_mfma_f32_16x16x32_bf16(bfrag[0][ks], hf.v, ACC_[0], 0, 0, 0); \
      ACC_[1] = __builtin_amdgcn_mfma_f32_16x16x32_bf16(bfrag[1][ks], hf.v, ACC_[1], 0, 0, 0); \
      ACC_[2] = __builtin_amdgcn_mfma_f32_16x16x32_bf16(bfrag[2][ks], hf.v, ACC_[2], 0, 0, 0); \
    } }

// epilogue for one chunk: lane holds P[f=t*16+4q+r][j=J0_+n]
#define CHUNK_EPI(J0_, I_, ACC_, L_, O_)                                        \
  { float pv[3][4];                                                             \
    float ss = 0.f;                                                             \
    _Pragma("unroll")                                                           \
    for (int t = 0; t < 3; ++t)                                                 \
      _Pragma("unroll")                                                         \
      for (int r = 0; r < 4; ++r) {                                             \
        const float pz = ACC_[t][r] + b2v[t][r];                                \
        pv[t][r] = pz;                                                          \
        ss = fmaf(pz, pz, ss);                                                  \
      }                                                                         \
    ss += __shfl_xor(ss, 16);                                                   \
    ss += __shfl_xor(ss, 32);                                                   \
    const int j = (J0_) + n;                                                    \
    const float ew = (j <= (I_))                                                \
        ? __builtin_amdgcn_exp2f(sqrtf(ss) * 1.44269504f) : 0.f;                \
    L_ += ew;                                                                   \
    _Pragma("unroll")                                                           \
    for (int t = 0; t < 3; ++t)                                                 \
      _Pragma("unroll")                                                         \
      for (int r = 0; r < 4; ++r)                                               \
        O_[t][r] = fmaf(ew, pv[t][r], O_[t][r]); }

// one row, DUAL chunk streams (c, c+4) stepping 8: two independent register
// streams (pbA/accA, pbB/accB) so gelu/MFMA/epilogue chains interleave.
#define PROCESS_ROW_DUAL(I_, ROW_, CSTART_, L_, O_)                             \
  { float av[3][8];                                                             \
    _Pragma("unroll")                                                           \
    for (int ks = 0; ks < 3; ++ks) {                                            \
      const float4 a0 = *(const float4*)&Arow[(size_t)(ROW_)*TWO_D + ks*32 + q8];     \
      const float4 a1 = *(const float4*)&Arow[(size_t)(ROW_)*TWO_D + ks*32 + q8 + 4]; \
      av[ks][0]=a0.x; av[ks][1]=a0.y; av[ks][2]=a0.z; av[ks][3]=a0.w;           \
      av[ks][4]=a1.x; av[ks][5]=a1.y; av[ks][6]=a1.z; av[ks][7]=a1.w;           \
    }                                                                           \
    const int nch = ((I_) + 16) >> 4;                                           \
    int c = (CSTART_);                                                          \
    const __hip_bfloat16* __restrict__ Bp =                                     \
        Bbase + (size_t)((c << 4) + n) * TWO_D;                                 \
    u32x4 pbA[3], pbB[3];                                                       \
    if (c < nch) LOAD_PB(pbA, Bp);                                              \
    if (c + 4 < nch) LOAD_PB(pbB, Bp + 64 * TWO_D);                             \
    for (; c + 4 < nch; c += 8) {                                               \
      const bool pfA = (c + 8) < nch;                                           \
      const bool pfB = (c + 12) < nch;                                          \
      const __hip_bfloat16* __restrict__ BpA = Bp + 128 * TWO_D;                \
      const __hip_bfloat16* __restrict__ BpB = Bp + 192 * TWO_D;                \
      f32x4 accA[3] = {{0.f,0.f,0.f,0.f},{0.f,0.f,0.f,0.f},{0.f,0.f,0.f,0.f}};  \
      f32x4 accB[3] = {{0.f,0.f,0.f,0.f},{0.f,0.f,0.f,0.f},{0.f,0.f,0.f,0.f}};  \
      CHUNK_MFMA(pbA, accA, pfA, BpA);                                          \
      CHUNK_MFMA(pbB, accB, pfB, BpB);                                          \
      CHUNK_EPI((c << 4), I_, accA, L_, O_);                                    \
      CHUNK_EPI(((c + 4) << 4), I_, accB, L_, O_);                              \
      Bp = BpA;                                                                 \
    }                                                                           \
    if (c < nch) {                                                              \
      f32x4 accA[3] = {{0.f,0.f,0.f,0.f},{0.f,0.f,0.f,0.f},{0.f,0.f,0.f,0.f}};  \
      CHUNK_MFMA(pbA, accA, false, Bp);                                         \
      CHUNK_EPI((c << 4), I_, accA, L_, O_);                                    \
    } }

// Kernel 2: one block per (batch, row-PAIR (p, 511-p)); 33 chunks per block
// (uniform), 1024 blocks all co-resident. Each wave: heavy-row chunks
// c=w,w+4,.. then light-row chunks continuing the mod-4 sequence; both rows
// processed with dual chunk streams for per-wave ILP.
__global__ __launch_bounds__(256) void pair_softmax_kernel(
        const float* __restrict__ Arow,
        const __hip_bfloat16* __restrict__ Brow,
        const __hip_bfloat16* __restrict__ W2T,
        const float* __restrict__ b2,
        float* __restrict__ out) {
    const int batch = blockIdx.x >> 8;        // 0..3
    const int pr = blockIdx.x & 255;          // 0..255
    const int iH = (NN - 1) - pr;             // 256..511
    const int iL = pr;                        // 0..255
    const int cH = (iH >> 4) + 1;             // 17..32; cH + cL = 33
    const int rowH = batch * NN + iH;
    const int rowL = batch * NN + iL;
    const __hip_bfloat16* __restrict__ Bbase = Brow + (size_t)batch * NN * TWO_D;

    const int tid = threadIdx.x;
    const int wave = tid >> 6;                // 0..3
    const int lane = tid & 63;
    const int n = lane & 15;   // j-local (C/D col); also W2T A-frag row f-local
    const int q = lane >> 4;   // quad
    const int q8 = q * 8;

    // W2T fragments (A-operand): lane holds W2T[f=t*16+n][ks*32+q8+0..7]
    bf16x8 bfrag[3][3];
#pragma unroll
    for (int t = 0; t < 3; ++t)
#pragma unroll
        for (int ks = 0; ks < 3; ++ks)
            bfrag[t][ks] = *(const bf16x8*)&W2T[(t * 16 + n) * TWO_D + ks * 32 + q8];
    // b2 for this lane's C/D rows: f = t*16 + 4q + r
    float b2v[3][4];
#pragma unroll
    for (int t = 0; t < 3; ++t)
#pragma unroll
        for (int r = 0; r < 4; ++r) b2v[t][r] = b2[t * 16 + 4 * q + r];

    float lH = 0.f, lL = 0.f;
    float oH[3][4] = {{0.f,0.f,0.f,0.f},{0.f,0.f,0.f,0.f},{0.f,0.f,0.f,0.f}};
    float oL[3][4] = {{0.f,0.f,0.f,0.f},{0.f,0.f,0.f,0.f},{0.f,0.f,0.f,0.f}};

    // Heavy row: chunks c ≡ wave (mod 4)
    PROCESS_ROW_DUAL(iH, rowH, wave, lH, oH);
    // Light row: global chunk index idx = cH + c ≡ wave (mod 4)
    const int cstartL = (wave + 128 - cH) & 3;
    PROCESS_ROW_DUAL(iL, rowL, cstartL, lL, oL);

    // ---- Final reduce over n (16 lanes; q bits untouched)
#pragma unroll
    for (int d = 1; d <= 8; d <<= 1) {
        lH += __shfl_xor(lH, d);
        lL += __shfl_xor(lL, d);
#pragma unroll
        for (int t = 0; t < 3; ++t)
#pragma unroll
            for (int r = 0; r < 4; ++r) {
                oH[t][r] += __shfl_xor(oH[t][r], d);
                oL[t][r] += __shfl_xor(oL[t][r], d);
            }
    }
    __shared__ float lred[4][2];
    __shared__ float ored[4][2][DD];
    if (n == 0) {
#pragma unroll
        for (int t = 0; t < 3; ++t)
#pragma unroll
            for (int r = 0; r < 4; ++r) {
                ored[wave][0][t * 16 + 4 * q + r] = oH[t][r];
                ored[wave][1][t * 16 + 4 * q + r] = oL[t][r];
            }
    }
    if (lane == 0) { lred[wave][0] = lH; lred[wave][1] = lL; }
    __syncthreads();
    if (tid < 2 * DD) {
        const int sel = tid / DD;
        const int f = tid - sel * DD;
        float L = 0.f, O = 0.f;
#pragma unroll
        for (int wv = 0; wv < 4; ++wv) {
            L += lred[wv][sel];
            O += ored[wv][sel][f];
        }
        const int row = sel ? rowL : rowH;
        out[row * DD + f] = O / L;
    }
}

extern "C" void kernel_launch(void* const* d_in, const int* in_sizes, int n_in,
                              void* d_out, int out_size, void* d_ws, size_t ws_size,
                              hipStream_t stream) {
    const float* x  = (const float*)d_in[0];
    const float* W1 = (const float*)d_in[1];
    const float* b1 = (const float*)d_in[2];
    const float* W2 = (const float*)d_in[3];
    const float* b2 = (const float*)d_in[4];
    float* outp = (float*)d_out;

    float* A = (float*)d_ws;                                    // 2048*96 fp32
    __hip_bfloat16* Bb  = (__hip_bfloat16*)(A + ROWS * TWO_D);  // 2048*96 bf16
    __hip_bfloat16* W2T = Bb + ROWS * TWO_D;                    // 48*96 bf16

    precompute_kernel<<<ROWS / 4 + 1, 256, 0, stream>>>(x, W1, b1, W2, A, Bb, W2T);
    pair_softmax_kernel<<<1024, 256, 0, stream>>>(A, Bb, W2T, b2, outp);
}